// Round 3
// baseline (3924.180 us; speedup 1.0000x reference)
//
#include <hip/hip_runtime.h>

typedef unsigned short u16;
typedef unsigned int u32;

// ---------- bf16 helpers ----------
__device__ __forceinline__ u16 f2bf(float f) {
  u32 u = __float_as_uint(f);
  u += 0x7FFFu + ((u >> 16) & 1u);
  return (u16)(u >> 16);
}
__device__ __forceinline__ float bf2f(u16 h) {
  return __uint_as_float(((u32)h) << 16);
}
__device__ __forceinline__ void unp2(u32 u, float& a, float& b) {
  a = __uint_as_float(u << 16);
  b = __uint_as_float(u & 0xFFFF0000u);
}
__device__ __forceinline__ u32 pk2(float a, float b) {
  return (u32)f2bf(a) | ((u32)f2bf(b) << 16);
}

// ---------- CSR build ----------
__global__ void k_hist(const int* __restrict__ seg, int* __restrict__ counts, int ne) {
  int i = blockIdx.x * blockDim.x + threadIdx.x, s = gridDim.x * blockDim.x;
  for (; i < ne; i += s) atomicAdd(&counts[seg[i]], 1);
}
__global__ void k_copyi(const int* __restrict__ a, int* __restrict__ b, int n) {
  int i = blockIdx.x * blockDim.x + threadIdx.x, s = gridDim.x * blockDim.x;
  for (; i < n; i += s) b[i] = a[i];
}
__global__ void k_fill(const int* __restrict__ seg, int* __restrict__ cursor,
                       int* __restrict__ eid, int ne) {
  int i = blockIdx.x * blockDim.x + threadIdx.x, s = gridDim.x * blockDim.x;
  for (; i < ne; i += s) { int pos = atomicAdd(&cursor[seg[i]], 1); eid[pos] = i; }
}
__global__ void k_exscan(const int* __restrict__ counts, int* __restrict__ offs, int n) {
  __shared__ int part[1024];
  int tid = threadIdx.x;
  int per = (n + 1023) >> 10;
  int start = tid * per;
  int s = 0;
  for (int k = 0; k < per; ++k) { int idx = start + k; if (idx < n) s += counts[idx]; }
  part[tid] = s; __syncthreads();
  for (int d = 1; d < 1024; d <<= 1) {
    int v = (tid >= d) ? part[tid - d] : 0;
    __syncthreads();
    part[tid] += v;
    __syncthreads();
  }
  int run = (tid == 0) ? 0 : part[tid - 1];
  for (int k = 0; k < per; ++k) { int idx = start + k; if (idx < n) { offs[idx] = run; run += counts[idx]; } }
  if (tid == 0) offs[n] = part[1023];
}

// ---------- fused 2-layer MLP: y = relu(x@W0+b0)@W1+b1 ; x f32, y bf16, W f32 ----------
__global__ __launch_bounds__(256) void k_mlp2(
    const float* __restrict__ x,
    const float* __restrict__ W0, const float* __restrict__ b0,
    const float* __restrict__ W1, const float* __restrict__ b1,
    u16* __restrict__ y, int n)
{
  __shared__ float xs[64][129];
  const int tid = threadIdx.x;
  const int r0 = blockIdx.x * 64;
  for (int t = tid; t < 64 * 32; t += 256) {
    int row = t >> 5, ch = t & 31; int gr = r0 + row;
    float4 v = make_float4(0.f, 0.f, 0.f, 0.f);
    if (gr < n) v = *(const float4*)(x + (size_t)gr * 128 + ch * 4);
    float* p = &xs[row][ch * 4];
    p[0] = v.x; p[1] = v.y; p[2] = v.z; p[3] = v.w;
  }
  __syncthreads();
  const int c0 = (tid & 15) * 8;
  const int rb = (tid >> 4) * 4;
  float acc[4][8];

  // layer 0
  {
    float4 bva = *(const float4*)(b0 + c0);
    float4 bvb = *(const float4*)(b0 + c0 + 4);
#pragma unroll
    for (int r = 0; r < 4; ++r) {
      acc[r][0] = bva.x; acc[r][1] = bva.y; acc[r][2] = bva.z; acc[r][3] = bva.w;
      acc[r][4] = bvb.x; acc[r][5] = bvb.y; acc[r][6] = bvb.z; acc[r][7] = bvb.w;
    }
    for (int k = 0; k < 128; ++k) {
      float4 wa = *(const float4*)(W0 + (size_t)k * 128 + c0);
      float4 wb = *(const float4*)(W0 + (size_t)k * 128 + c0 + 4);
#pragma unroll
      for (int r = 0; r < 4; ++r) {
        float xv = xs[rb + r][k];
        acc[r][0] = fmaf(xv, wa.x, acc[r][0]);
        acc[r][1] = fmaf(xv, wa.y, acc[r][1]);
        acc[r][2] = fmaf(xv, wa.z, acc[r][2]);
        acc[r][3] = fmaf(xv, wa.w, acc[r][3]);
        acc[r][4] = fmaf(xv, wb.x, acc[r][4]);
        acc[r][5] = fmaf(xv, wb.y, acc[r][5]);
        acc[r][6] = fmaf(xv, wb.z, acc[r][6]);
        acc[r][7] = fmaf(xv, wb.w, acc[r][7]);
      }
    }
  }
  __syncthreads();
#pragma unroll
  for (int r = 0; r < 4; ++r)
#pragma unroll
    for (int c = 0; c < 8; ++c)
      xs[rb + r][c0 + c] = fmaxf(acc[r][c], 0.f);
  __syncthreads();

  // layer 1
  {
    float4 bva = *(const float4*)(b1 + c0);
    float4 bvb = *(const float4*)(b1 + c0 + 4);
#pragma unroll
    for (int r = 0; r < 4; ++r) {
      acc[r][0] = bva.x; acc[r][1] = bva.y; acc[r][2] = bva.z; acc[r][3] = bva.w;
      acc[r][4] = bvb.x; acc[r][5] = bvb.y; acc[r][6] = bvb.z; acc[r][7] = bvb.w;
    }
    for (int k = 0; k < 128; ++k) {
      float4 wa = *(const float4*)(W1 + (size_t)k * 128 + c0);
      float4 wb = *(const float4*)(W1 + (size_t)k * 128 + c0 + 4);
#pragma unroll
      for (int r = 0; r < 4; ++r) {
        float xv = xs[rb + r][k];
        acc[r][0] = fmaf(xv, wa.x, acc[r][0]);
        acc[r][1] = fmaf(xv, wa.y, acc[r][1]);
        acc[r][2] = fmaf(xv, wa.z, acc[r][2]);
        acc[r][3] = fmaf(xv, wa.w, acc[r][3]);
        acc[r][4] = fmaf(xv, wb.x, acc[r][4]);
        acc[r][5] = fmaf(xv, wb.y, acc[r][5]);
        acc[r][6] = fmaf(xv, wb.z, acc[r][6]);
        acc[r][7] = fmaf(xv, wb.w, acc[r][7]);
      }
    }
  }
#pragma unroll
  for (int r = 0; r < 4; ++r) {
    int gr = r0 + rb + r;
    if (gr < n) {
      uint4 o;
      o.x = pk2(acc[r][0], acc[r][1]);
      o.y = pk2(acc[r][2], acc[r][3]);
      o.z = pk2(acc[r][4], acc[r][5]);
      o.w = pk2(acc[r][6], acc[r][7]);
      *(uint4*)(y + (size_t)gr * 128 + c0) = o;
    }
  }
}

// ---------- per-row dual dots: ox[r]=x[r].ax (x f32)  oy[r]=y[r].ay (y bf16) ----------
__global__ __launch_bounds__(256) void k_dots(
    const float* __restrict__ x, const u16* __restrict__ y,
    const float* __restrict__ ax, const float* __restrict__ ay,
    float* __restrict__ ox, float* __restrict__ oy, int n)
{
  int lane = threadIdx.x & 63;
  int wid = (blockIdx.x * blockDim.x + threadIdx.x) >> 6;
  int nw = (gridDim.x * blockDim.x) >> 6;
  float2 axv = *(const float2*)(ax + lane * 2);
  float2 ayv = *(const float2*)(ay + lane * 2);
  for (int r = wid; r < n; r += nw) {
    float2 xv = *(const float2*)(x + (size_t)r * 128 + lane * 2);
    u32 yv = *(const u32*)(y + (size_t)r * 128 + lane * 2);
    float y0, y1; unp2(yv, y0, y1);
    float px = xv.x * axv.x + xv.y * axv.y;
    float py = y0 * ayv.x + y1 * ayv.y;
#pragma unroll
    for (int d = 32; d >= 1; d >>= 1) { px += __shfl_xor(px, d); py += __shfl_xor(py, d); }
    if (lane == 0) { ox[r] = px; oy[r] = py; }
  }
}

// ---------- attention softmax (both segmented by clause), 16 lanes/clause ----------
__global__ __launch_bounds__(256) void k_attw(
    const int* __restrict__ c_off, const int* __restrict__ c_eid, const int* __restrict__ l_edge,
    const float* __restrict__ ca, const float* __restrict__ cb,
    const float* __restrict__ la, const float* __restrict__ lb,
    float* __restrict__ w1s, float* __restrict__ w2e, int C)
{
  int gid = (blockIdx.x * blockDim.x + threadIdx.x) >> 4;
  int lane = threadIdx.x & 15;
  if (gid >= C) return;
  int off = c_off[gid], end = c_off[gid + 1];
  if (off == end) return;
  float cav = ca[gid], cbv = cb[gid];
  float m1 = -3.0e38f, m2 = -3.0e38f;
  for (int j = off + lane; j < end; j += 16) {
    int e = c_eid[j]; int l = l_edge[e];
    float s1 = cav + la[l]; s1 = s1 > 0.f ? s1 : 0.2f * s1;
    float s2 = lb[l] + cbv; s2 = s2 > 0.f ? s2 : 0.2f * s2;
    w1s[j] = s1; w2e[e] = s2;
    m1 = fmaxf(m1, s1); m2 = fmaxf(m2, s2);
  }
#pragma unroll
  for (int d = 8; d >= 1; d >>= 1) { m1 = fmaxf(m1, __shfl_xor(m1, d, 16)); m2 = fmaxf(m2, __shfl_xor(m2, d, 16)); }
  float z1 = 0.f, z2 = 0.f;
  for (int j = off + lane; j < end; j += 16) {
    int e = c_eid[j];
    float e1 = __expf(w1s[j] - m1);
    float e2 = __expf(w2e[e] - m2);
    w1s[j] = e1; w2e[e] = e2; z1 += e1; z2 += e2;
  }
#pragma unroll
  for (int d = 8; d >= 1; d >>= 1) { z1 += __shfl_xor(z1, d, 16); z2 += __shfl_xor(z2, d, 16); }
  float i1 = 1.f / (z1 + 1e-16f), i2 = 1.f / (z2 + 1e-16f);
  for (int j = off + lane; j < end; j += 16) {
    int e = c_eid[j];
    w1s[j] *= i1; w2e[e] *= i2;
  }
}

// ---------- weighted segment aggregation: out[seg] = sum w * feat[other[e]] ----------
__global__ __launch_bounds__(128) void k_aggr(
    const int* __restrict__ offs, const int* __restrict__ eids, const int* __restrict__ other,
    const float* __restrict__ w, int w_by_pos,
    const u16* __restrict__ feat, u16* __restrict__ out, int nseg)
{
  int seg = blockIdx.x; int d = threadIdx.x;
  if (seg >= nseg) return;
  int off = offs[seg], end = offs[seg + 1];
  float acc = 0.f;
  for (int j = off; j < end; ++j) {
    int e = eids[j];
    float wv = w_by_pos ? w[j] : w[e];
    int row = other[e];
    acc = fmaf(wv, bf2f(feat[(size_t)row * 128 + d]), acc);
  }
  out[(size_t)seg * 128 + d] = f2bf(acc);
}

// ---------- update GEMM: out[r] = concat(xa[r], xb[r] [, xc[r^1]]) @ W + bias ----------
// xa f32 (prev out slice), xb/xc bf16, W/bias f32, out f32 (next out slice)
template <int KTOT>
__global__ __launch_bounds__(256) void k_update(
    const float* __restrict__ xa, const u16* __restrict__ xb, const u16* __restrict__ xc,
    const float* __restrict__ W, const float* __restrict__ bias,
    float* __restrict__ ob, int n)
{
  __shared__ float xs[32][KTOT + 1];
  const int tid = threadIdx.x;
  const int r0 = blockIdx.x * 32;
  for (int t = tid; t < 32 * 32; t += 256) {
    int row = t >> 5, ch = t & 31; int gr = r0 + row;
    float4 v = make_float4(0.f, 0.f, 0.f, 0.f);
    if (gr < n) v = *(const float4*)(xa + (size_t)gr * 128 + ch * 4);
    float* p = &xs[row][ch * 4];
    p[0] = v.x; p[1] = v.y; p[2] = v.z; p[3] = v.w;
  }
  for (int t = tid; t < 32 * 16; t += 256) {
    int row = t >> 4, ch = t & 15; int gr = r0 + row;
    uint4 v = make_uint4(0, 0, 0, 0);
    if (gr < n) v = *(const uint4*)(xb + (size_t)gr * 128 + ch * 8);
    float f0, f1, f2, f3, f4, f5, f6, f7;
    unp2(v.x, f0, f1); unp2(v.y, f2, f3); unp2(v.z, f4, f5); unp2(v.w, f6, f7);
    float* p = &xs[row][128 + ch * 8];
    p[0] = f0; p[1] = f1; p[2] = f2; p[3] = f3; p[4] = f4; p[5] = f5; p[6] = f6; p[7] = f7;
  }
  if (KTOT > 256) {
    for (int t = tid; t < 32 * 16; t += 256) {
      int row = t >> 4, ch = t & 15; int gr = r0 + row;
      uint4 v = make_uint4(0, 0, 0, 0);
      if (gr < n) v = *(const uint4*)(xc + (size_t)(gr ^ 1) * 128 + ch * 8);
      float f0, f1, f2, f3, f4, f5, f6, f7;
      unp2(v.x, f0, f1); unp2(v.y, f2, f3); unp2(v.z, f4, f5); unp2(v.w, f6, f7);
      float* p = &xs[row][256 + ch * 8];
      p[0] = f0; p[1] = f1; p[2] = f2; p[3] = f3; p[4] = f4; p[5] = f5; p[6] = f6; p[7] = f7;
    }
  }
  __syncthreads();
  const int c0 = (tid & 15) * 8;
  const int rb = (tid >> 4) * 2;
  float acc[2][8];
  float4 bva = *(const float4*)(bias + c0);
  float4 bvb = *(const float4*)(bias + c0 + 4);
#pragma unroll
  for (int r = 0; r < 2; ++r) {
    acc[r][0] = bva.x; acc[r][1] = bva.y; acc[r][2] = bva.z; acc[r][3] = bva.w;
    acc[r][4] = bvb.x; acc[r][5] = bvb.y; acc[r][6] = bvb.z; acc[r][7] = bvb.w;
  }
  for (int k = 0; k < KTOT; ++k) {
    float4 wa = *(const float4*)(W + (size_t)k * 128 + c0);
    float4 wb = *(const float4*)(W + (size_t)k * 128 + c0 + 4);
#pragma unroll
    for (int r = 0; r < 2; ++r) {
      float xv = xs[rb + r][k];
      acc[r][0] = fmaf(xv, wa.x, acc[r][0]);
      acc[r][1] = fmaf(xv, wa.y, acc[r][1]);
      acc[r][2] = fmaf(xv, wa.z, acc[r][2]);
      acc[r][3] = fmaf(xv, wa.w, acc[r][3]);
      acc[r][4] = fmaf(xv, wb.x, acc[r][4]);
      acc[r][5] = fmaf(xv, wb.y, acc[r][5]);
      acc[r][6] = fmaf(xv, wb.z, acc[r][6]);
      acc[r][7] = fmaf(xv, wb.w, acc[r][7]);
    }
  }
#pragma unroll
  for (int r = 0; r < 2; ++r) {
    int gr = r0 + rb + r;
    if (gr < n) {
      *(float4*)(ob + (size_t)gr * 128 + c0)     = make_float4(acc[r][0], acc[r][1], acc[r][2], acc[r][3]);
      *(float4*)(ob + (size_t)gr * 128 + c0 + 4) = make_float4(acc[r][4], acc[r][5], acc[r][6], acc[r][7]);
    }
  }
}

// ---------- host launch ----------
extern "C" void kernel_launch(void* const* d_in, const int* in_sizes, int n_in,
                              void* d_out, int out_size, void* d_ws, size_t ws_size,
                              hipStream_t stream)
{
  const float* l_emb0  = (const float*)d_in[0];
  const float* c_emb0  = (const float*)d_in[1];
  const float* l2c_W   = (const float*)d_in[2];
  const float* l2c_b   = (const float*)d_in[3];
  const float* c2l_W   = (const float*)d_in[4];
  const float* c2l_b   = (const float*)d_in[5];
  const float* l2l_W   = (const float*)d_in[6];
  const float* l2l_b   = (const float*)d_in[7];
  const float* c_att   = (const float*)d_in[8];
  const float* l_att   = (const float*)d_in[9];
  const float* c_upd_W = (const float*)d_in[10];
  const float* c_upd_b = (const float*)d_in[11];
  const float* l_upd_W = (const float*)d_in[12];
  const float* l_upd_b = (const float*)d_in[13];
  const int* l_edge    = (const int*)d_in[14];
  const int* c_edge    = (const int*)d_in[15];

  const int L = in_sizes[0] / 128;
  const int C = in_sizes[1] / 128;
  const int E = in_sizes[14];

  float* out_l = (float*)d_out;                    // [5][L][128] f32
  float* out_c = out_l + (size_t)5 * L * 128;      // [5][C][128] f32

  // workspace (~80 MB total)
  char* wsb = (char*)d_ws;
  size_t off = 0;
  auto alloc = [&](size_t bytes) -> char* {
    char* p = wsb + off;
    off = (off + bytes + 255) & ~(size_t)255;
    return p;
  };
  u16* lbuf = (u16*)alloc((size_t)L * 128 * 2);   // l_msg_feat, later l2l_msg
  u16* cmsg = (u16*)alloc((size_t)C * 128 * 2);
  u16* lagg = (u16*)alloc((size_t)L * 128 * 2);
  u16* cagg = (u16*)alloc((size_t)C * 128 * 2);
  float* la  = (float*)alloc((size_t)L * 4);
  float* lb  = (float*)alloc((size_t)L * 4);
  float* ca  = (float*)alloc((size_t)C * 4);
  float* cb  = (float*)alloc((size_t)C * 4);
  float* w1s = (float*)alloc((size_t)E * 4);
  float* w2e = (float*)alloc((size_t)E * 4);
  int* c_off_a = (int*)alloc((size_t)(C + 1) * 4);
  int* l_off_a = (int*)alloc((size_t)(L + 1) * 4);
  int* c_eid   = (int*)alloc((size_t)E * 4);
  int* l_eid   = (int*)alloc((size_t)E * 4);
  int* tmp     = (int*)alloc((size_t)(L + 1) * 4);
  (void)ws_size; (void)n_in; (void)out_size;

  // slice 0 = copy of f32 inputs
  hipMemcpyAsync(out_l, l_emb0, (size_t)L * 128 * 4, hipMemcpyDeviceToDevice, stream);
  hipMemcpyAsync(out_c, c_emb0, (size_t)C * 128 * 4, hipMemcpyDeviceToDevice, stream);

  // clause CSR
  hipMemsetAsync(tmp, 0, (size_t)C * 4, stream);
  k_hist<<<1024, 256, 0, stream>>>(c_edge, tmp, E);
  k_exscan<<<1, 1024, 0, stream>>>(tmp, c_off_a, C);
  k_copyi<<<256, 256, 0, stream>>>(c_off_a, tmp, C);
  k_fill<<<1024, 256, 0, stream>>>(c_edge, tmp, c_eid, E);
  // literal CSR
  hipMemsetAsync(tmp, 0, (size_t)L * 4, stream);
  k_hist<<<1024, 256, 0, stream>>>(l_edge, tmp, E);
  k_exscan<<<1, 1024, 0, stream>>>(tmp, l_off_a, L);
  k_copyi<<<256, 256, 0, stream>>>(l_off_a, tmp, L);
  k_fill<<<1024, 256, 0, stream>>>(l_edge, tmp, l_eid, E);

  for (int i = 0; i < 4; ++i) {
    const float* OL = out_l + (size_t)i * L * 128;       // l_emb at iter i (f32)
    const float* OC = out_c + (size_t)i * C * 128;       // c_emb at iter i (f32)
    float* OLn = out_l + (size_t)(i + 1) * L * 128;
    float* OCn = out_c + (size_t)(i + 1) * C * 128;

    const float* W0l = l2c_W + (size_t)i * 2 * 128 * 128;
    const float* b0l = l2c_b + (size_t)i * 2 * 128;
    const float* W0c = c2l_W + (size_t)i * 2 * 128 * 128;
    const float* b0c = c2l_b + (size_t)i * 2 * 128;
    const float* W0x = l2l_W + (size_t)i * 2 * 128 * 128;
    const float* b0x = l2l_b + (size_t)i * 2 * 128;

    // message MLPs
    k_mlp2<<<(L + 63) / 64, 256, 0, stream>>>(OL, W0l, b0l, W0l + 128 * 128, b0l + 128, lbuf, L);
    k_mlp2<<<(C + 63) / 64, 256, 0, stream>>>(OC, W0c, b0c, W0c + 128 * 128, b0c + 128, cmsg, C);

    // attention scalar factors:
    // lb = l_emb . l_att[:128], la = l_msg_feat . c_att[128:]
    k_dots<<<1024, 256, 0, stream>>>(OL, lbuf, l_att + (size_t)i * 256, c_att + (size_t)i * 256 + 128, lb, la, L);
    // ca = c_emb . c_att[:128], cb = c_msg_feat . l_att[128:]
    k_dots<<<512, 256, 0, stream>>>(OC, cmsg, c_att + (size_t)i * 256, l_att + (size_t)i * 256 + 128, ca, cb, C);

    // segmented softmax (both over clause segments; reference quirk)
    k_attw<<<(C * 16 + 255) / 256, 256, 0, stream>>>(c_off_a, c_eid, l_edge, ca, cb, la, lb, w1s, w2e, C);

    // aggregations
    k_aggr<<<C, 128, 0, stream>>>(c_off_a, c_eid, l_edge, w1s, 1, lbuf, cagg, C);
    k_aggr<<<L, 128, 0, stream>>>(l_off_a, l_eid, c_edge, w2e, 0, cmsg, lagg, L);

    // l2l MLP (after clause aggregation freed lbuf)
    k_mlp2<<<(L + 63) / 64, 256, 0, stream>>>(OL, W0x, b0x, W0x + 128 * 128, b0x + 128, lbuf, L);

    // clause update -> next slice
    k_update<256><<<(C + 31) / 32, 256, 0, stream>>>(
        OC, cagg, (const u16*)nullptr,
        c_upd_W + (size_t)i * 256 * 128, c_upd_b + (size_t)i * 128, OCn, C);

    // literal update -> next slice (xc read with XOR-1 row flip)
    k_update<384><<<(L + 31) / 32, 256, 0, stream>>>(
        OL, lagg, lbuf,
        l_upd_W + (size_t)i * 384 * 128, l_upd_b + (size_t)i * 128, OLn, L);
  }
}

// Round 4
// 1860.801 us; speedup vs baseline: 2.1089x; 2.1089x over previous
//
#include <hip/hip_runtime.h>

typedef unsigned short u16;
typedef unsigned int u32;
typedef __attribute__((ext_vector_type(8))) short s8v;   // 8 bf16 = 4 VGPR
typedef __attribute__((ext_vector_type(4))) float f4v;   // MFMA accum

// ---------- bf16 helpers ----------
__device__ __forceinline__ u16 f2bf(float f) {
  u32 u = __float_as_uint(f);
  u += 0x7FFFu + ((u >> 16) & 1u);
  return (u16)(u >> 16);
}
__device__ __forceinline__ float bf2f(u16 h) {
  return __uint_as_float(((u32)h) << 16);
}
__device__ __forceinline__ void unp2(u32 u, float& a, float& b) {
  a = __uint_as_float(u << 16);
  b = __uint_as_float(u & 0xFFFF0000u);
}

// ---------- CSR build ----------
__global__ void k_hist(const int* __restrict__ seg, int* __restrict__ counts, int ne) {
  int i = blockIdx.x * blockDim.x + threadIdx.x, s = gridDim.x * blockDim.x;
  for (; i < ne; i += s) atomicAdd(&counts[seg[i]], 1);
}
__global__ void k_copyi(const int* __restrict__ a, int* __restrict__ b, int n) {
  int i = blockIdx.x * blockDim.x + threadIdx.x, s = gridDim.x * blockDim.x;
  for (; i < n; i += s) b[i] = a[i];
}
__global__ void k_fill(const int* __restrict__ seg, int* __restrict__ cursor,
                       int* __restrict__ eid, int ne) {
  int i = blockIdx.x * blockDim.x + threadIdx.x, s = gridDim.x * blockDim.x;
  for (; i < ne; i += s) { int pos = atomicAdd(&cursor[seg[i]], 1); eid[pos] = i; }
}
__global__ void k_exscan(const int* __restrict__ counts, int* __restrict__ offs, int n) {
  __shared__ int part[1024];
  int tid = threadIdx.x;
  int per = (n + 1023) >> 10;
  int start = tid * per;
  int s = 0;
  for (int k = 0; k < per; ++k) { int idx = start + k; if (idx < n) s += counts[idx]; }
  part[tid] = s; __syncthreads();
  for (int d = 1; d < 1024; d <<= 1) {
    int v = (tid >= d) ? part[tid - d] : 0;
    __syncthreads();
    part[tid] += v;
    __syncthreads();
  }
  int run = (tid == 0) ? 0 : part[tid - 1];
  for (int k = 0; k < per; ++k) { int idx = start + k; if (idx < n) { offs[idx] = run; run += counts[idx]; } }
  if (tid == 0) offs[n] = part[1023];
}

// ---------- weight repack: f32 [K][128] -> bf16 MFMA B-frag layout ----------
// frag (kc,nt): elem j of lane l = W[kc*32 + (l>>4)*8 + j][nt*16 + (l&15)]
// dst index = ((kc*8+nt)*64 + lane)*8 + j
// regions per iter (elems): l2c(2x16384) c2l(2x16384) l2l(2x16384) c_upd(32768) l_upd(49152) = 180224
__global__ void k_packW(const float* __restrict__ l2c_W, const float* __restrict__ c2l_W,
                        const float* __restrict__ l2l_W, const float* __restrict__ c_upd_W,
                        const float* __restrict__ l_upd_W, u16* __restrict__ dst, int total) {
  int o = blockIdx.x * blockDim.x + threadIdx.x;
  if (o >= total) return;
  int it = o / 180224;
  int r = o - it * 180224;
  const float* src;
  int o2;
  if (r < 98304) {
    int m = r >> 14;           // 0..5
    o2 = r & 16383;
    if (m < 2)      src = l2c_W + ((size_t)it * 2 + m) * 16384;
    else if (m < 4) src = c2l_W + ((size_t)it * 2 + (m - 2)) * 16384;
    else            src = l2l_W + ((size_t)it * 2 + (m - 4)) * 16384;
  } else if (r < 131072) {
    o2 = r - 98304;  src = c_upd_W + (size_t)it * 32768;
  } else {
    o2 = r - 131072; src = l_upd_W + (size_t)it * 49152;
  }
  int j = o2 & 7, lane = (o2 >> 3) & 63, f = o2 >> 9;
  int nt = f & 7, kc = f >> 3;
  int k = kc * 32 + ((lane >> 4) << 3) + j;
  int nn = nt * 16 + (lane & 15);
  dst[o] = f2bf(src[(size_t)k * 128 + nn]);
}

// ---------- fused 2-layer MLP via MFMA: y = relu(x@W0+b0)@W1+b1 ----------
// x f32, packed bf16 weights, y bf16. 256 thr = 4 waves, 64 rows/block.
__global__ __launch_bounds__(256) void k_mlp2_mfma(
    const float* __restrict__ x,
    const u16* __restrict__ pW0, const float* __restrict__ b0,
    const u16* __restrict__ pW1, const float* __restrict__ b1,
    u16* __restrict__ y, int n)
{
  __shared__ u16 xs[64][136];
  __shared__ u16 hs[64][136];
  const int tid = threadIdx.x;
  const int lane = tid & 63;
  const int w = tid >> 6;
  const int r0 = blockIdx.x * 64;
  for (int t = tid; t < 64 * 32; t += 256) {
    int row = t >> 5, ch = t & 31; int gr = r0 + row;
    float4 v = make_float4(0.f, 0.f, 0.f, 0.f);
    if (gr < n) v = *(const float4*)(x + (size_t)gr * 128 + ch * 4);
    u16* p = &xs[row][ch * 4];
    p[0] = f2bf(v.x); p[1] = f2bf(v.y); p[2] = f2bf(v.z); p[3] = f2bf(v.w);
  }
  __syncthreads();
  const int arow = w * 16 + (lane & 15);
  const int kgrp = (lane >> 4) * 8;
  const int dcol = lane & 15;
  const int drow0 = w * 16 + (lane >> 4) * 4;
  f4v acc[8];
  // layer 0
#pragma unroll
  for (int nt = 0; nt < 8; ++nt) {
    float bv = b0[nt * 16 + dcol];
    acc[nt] = (f4v){bv, bv, bv, bv};
  }
#pragma unroll
  for (int kc = 0; kc < 4; ++kc) {
    s8v a = *(const s8v*)&xs[arow][kc * 32 + kgrp];
#pragma unroll
    for (int nt = 0; nt < 8; ++nt) {
      s8v b = *(const s8v*)(pW0 + ((size_t)(kc * 8 + nt) * 64 + lane) * 8);
      acc[nt] = __builtin_amdgcn_mfma_f32_16x16x32_bf16(a, b, acc[nt], 0, 0, 0);
    }
  }
#pragma unroll
  for (int nt = 0; nt < 8; ++nt)
#pragma unroll
    for (int r = 0; r < 4; ++r)
      hs[drow0 + r][nt * 16 + dcol] = f2bf(fmaxf(acc[nt][r], 0.f));
  __syncthreads();
  // layer 1
#pragma unroll
  for (int nt = 0; nt < 8; ++nt) {
    float bv = b1[nt * 16 + dcol];
    acc[nt] = (f4v){bv, bv, bv, bv};
  }
#pragma unroll
  for (int kc = 0; kc < 4; ++kc) {
    s8v a = *(const s8v*)&hs[arow][kc * 32 + kgrp];
#pragma unroll
    for (int nt = 0; nt < 8; ++nt) {
      s8v b = *(const s8v*)(pW1 + ((size_t)(kc * 8 + nt) * 64 + lane) * 8);
      acc[nt] = __builtin_amdgcn_mfma_f32_16x16x32_bf16(a, b, acc[nt], 0, 0, 0);
    }
  }
#pragma unroll
  for (int nt = 0; nt < 8; ++nt)
#pragma unroll
    for (int r = 0; r < 4; ++r) {
      int gr = r0 + drow0 + r;
      if (gr < n) y[(size_t)gr * 128 + nt * 16 + dcol] = f2bf(acc[nt][r]);
    }
}

// ---------- update GEMM via MFMA: out = concat(xa, xb [, xc[r^1]]) @ W + bias ----------
// xa f32, xb/xc bf16, out f32. 256 thr = 4 waves, 64 rows/block.
template <int KTOT>
__global__ __launch_bounds__(256) void k_upd_mfma(
    const float* __restrict__ xa, const u16* __restrict__ xb, const u16* __restrict__ xc,
    const u16* __restrict__ pW, const float* __restrict__ bias,
    float* __restrict__ ob, int n)
{
  constexpr int KP = KTOT + 8;
  __shared__ u16 xs[64][KP];
  const int tid = threadIdx.x;
  const int lane = tid & 63;
  const int w = tid >> 6;
  const int r0 = blockIdx.x * 64;
  for (int t = tid; t < 64 * 32; t += 256) {
    int row = t >> 5, ch = t & 31; int gr = r0 + row;
    float4 v = make_float4(0.f, 0.f, 0.f, 0.f);
    if (gr < n) v = *(const float4*)(xa + (size_t)gr * 128 + ch * 4);
    u16* p = &xs[row][ch * 4];
    p[0] = f2bf(v.x); p[1] = f2bf(v.y); p[2] = f2bf(v.z); p[3] = f2bf(v.w);
  }
  for (int t = tid; t < 64 * 16; t += 256) {
    int row = t >> 4, ch = t & 15; int gr = r0 + row;
    uint4 v = make_uint4(0, 0, 0, 0);
    if (gr < n) v = *(const uint4*)(xb + (size_t)gr * 128 + ch * 8);
    *(uint4*)&xs[row][128 + ch * 8] = v;
  }
  if (KTOT > 256) {
    for (int t = tid; t < 64 * 16; t += 256) {
      int row = t >> 4, ch = t & 15; int gr = r0 + row;
      uint4 v = make_uint4(0, 0, 0, 0);
      if (gr < n) v = *(const uint4*)(xc + (size_t)(gr ^ 1) * 128 + ch * 8);
      *(uint4*)&xs[row][256 + ch * 8] = v;
    }
  }
  __syncthreads();
  const int arow = w * 16 + (lane & 15);
  const int kgrp = (lane >> 4) * 8;
  const int dcol = lane & 15;
  const int drow0 = w * 16 + (lane >> 4) * 4;
  f4v acc[8];
#pragma unroll
  for (int nt = 0; nt < 8; ++nt) {
    float bv = bias[nt * 16 + dcol];
    acc[nt] = (f4v){bv, bv, bv, bv};
  }
#pragma unroll
  for (int kc = 0; kc < KTOT / 32; ++kc) {
    s8v a = *(const s8v*)&xs[arow][kc * 32 + kgrp];
#pragma unroll
    for (int nt = 0; nt < 8; ++nt) {
      s8v b = *(const s8v*)(pW + ((size_t)(kc * 8 + nt) * 64 + lane) * 8);
      acc[nt] = __builtin_amdgcn_mfma_f32_16x16x32_bf16(a, b, acc[nt], 0, 0, 0);
    }
  }
#pragma unroll
  for (int nt = 0; nt < 8; ++nt)
#pragma unroll
    for (int r = 0; r < 4; ++r) {
      int gr = r0 + drow0 + r;
      if (gr < n) ob[(size_t)gr * 128 + nt * 16 + dcol] = acc[nt][r];
    }
}

// ---------- per-row dual dots: ox[r]=x[r].ax (x f32)  oy[r]=y[r].ay (y bf16) ----------
__global__ __launch_bounds__(256) void k_dots(
    const float* __restrict__ x, const u16* __restrict__ y,
    const float* __restrict__ ax, const float* __restrict__ ay,
    float* __restrict__ ox, float* __restrict__ oy, int n)
{
  int lane = threadIdx.x & 63;
  int wid = (blockIdx.x * blockDim.x + threadIdx.x) >> 6;
  int nw = (gridDim.x * blockDim.x) >> 6;
  float2 axv = *(const float2*)(ax + lane * 2);
  float2 ayv = *(const float2*)(ay + lane * 2);
  for (int r = wid; r < n; r += nw) {
    float2 xv = *(const float2*)(x + (size_t)r * 128 + lane * 2);
    u32 yv = *(const u32*)(y + (size_t)r * 128 + lane * 2);
    float y0, y1; unp2(yv, y0, y1);
    float px = xv.x * axv.x + xv.y * axv.y;
    float py = y0 * ayv.x + y1 * ayv.y;
#pragma unroll
    for (int d = 32; d >= 1; d >>= 1) { px += __shfl_xor(px, d); py += __shfl_xor(py, d); }
    if (lane == 0) { ox[r] = px; oy[r] = py; }
  }
}

// ---------- attention softmax (both segmented by clause), 16 lanes/clause ----------
__global__ __launch_bounds__(256) void k_attw(
    const int* __restrict__ c_off, const int* __restrict__ c_eid, const int* __restrict__ l_edge,
    const float* __restrict__ ca, const float* __restrict__ cb,
    const float* __restrict__ la, const float* __restrict__ lb,
    float* __restrict__ w1s, float* __restrict__ w2e, int C)
{
  int gid = (blockIdx.x * blockDim.x + threadIdx.x) >> 4;
  int lane = threadIdx.x & 15;
  if (gid >= C) return;
  int off = c_off[gid], end = c_off[gid + 1];
  if (off == end) return;
  float cav = ca[gid], cbv = cb[gid];
  float m1 = -3.0e38f, m2 = -3.0e38f;
  for (int j = off + lane; j < end; j += 16) {
    int e = c_eid[j]; int l = l_edge[e];
    float s1 = cav + la[l]; s1 = s1 > 0.f ? s1 : 0.2f * s1;
    float s2 = lb[l] + cbv; s2 = s2 > 0.f ? s2 : 0.2f * s2;
    w1s[j] = s1; w2e[e] = s2;
    m1 = fmaxf(m1, s1); m2 = fmaxf(m2, s2);
  }
#pragma unroll
  for (int d = 8; d >= 1; d >>= 1) { m1 = fmaxf(m1, __shfl_xor(m1, d, 16)); m2 = fmaxf(m2, __shfl_xor(m2, d, 16)); }
  float z1 = 0.f, z2 = 0.f;
  for (int j = off + lane; j < end; j += 16) {
    int e = c_eid[j];
    float e1 = __expf(w1s[j] - m1);
    float e2 = __expf(w2e[e] - m2);
    w1s[j] = e1; w2e[e] = e2; z1 += e1; z2 += e2;
  }
#pragma unroll
  for (int d = 8; d >= 1; d >>= 1) { z1 += __shfl_xor(z1, d, 16); z2 += __shfl_xor(z2, d, 16); }
  float i1 = 1.f / (z1 + 1e-16f), i2 = 1.f / (z2 + 1e-16f);
  for (int j = off + lane; j < end; j += 16) {
    int e = c_eid[j];
    w1s[j] *= i1; w2e[e] *= i2;
  }
}

// ---------- weighted segment aggregation: out[seg] = sum w * feat[other[e]] ----------
__global__ __launch_bounds__(128) void k_aggr(
    const int* __restrict__ offs, const int* __restrict__ eids, const int* __restrict__ other,
    const float* __restrict__ w, int w_by_pos,
    const u16* __restrict__ feat, u16* __restrict__ out, int nseg)
{
  int seg = blockIdx.x; int d = threadIdx.x;
  if (seg >= nseg) return;
  int off = offs[seg], end = offs[seg + 1];
  float acc = 0.f;
  for (int j = off; j < end; ++j) {
    int e = eids[j];
    float wv = w_by_pos ? w[j] : w[e];
    int row = other[e];
    acc = fmaf(wv, bf2f(feat[(size_t)row * 128 + d]), acc);
  }
  out[(size_t)seg * 128 + d] = f2bf(acc);
}

// ---------- host launch ----------
extern "C" void kernel_launch(void* const* d_in, const int* in_sizes, int n_in,
                              void* d_out, int out_size, void* d_ws, size_t ws_size,
                              hipStream_t stream)
{
  const float* l_emb0  = (const float*)d_in[0];
  const float* c_emb0  = (const float*)d_in[1];
  const float* l2c_W   = (const float*)d_in[2];
  const float* l2c_b   = (const float*)d_in[3];
  const float* c2l_W   = (const float*)d_in[4];
  const float* c2l_b   = (const float*)d_in[5];
  const float* l2l_W   = (const float*)d_in[6];
  const float* l2l_b   = (const float*)d_in[7];
  const float* c_att   = (const float*)d_in[8];
  const float* l_att   = (const float*)d_in[9];
  const float* c_upd_W = (const float*)d_in[10];
  const float* c_upd_b = (const float*)d_in[11];
  const float* l_upd_W = (const float*)d_in[12];
  const float* l_upd_b = (const float*)d_in[13];
  const int* l_edge    = (const int*)d_in[14];
  const int* c_edge    = (const int*)d_in[15];

  const int L = in_sizes[0] / 128;
  const int C = in_sizes[1] / 128;
  const int E = in_sizes[14];

  float* out_l = (float*)d_out;                    // [5][L][128] f32
  float* out_c = out_l + (size_t)5 * L * 128;      // [5][C][128] f32

  char* wsb = (char*)d_ws;
  size_t off = 0;
  auto alloc = [&](size_t bytes) -> char* {
    char* p = wsb + off;
    off = (off + bytes + 255) & ~(size_t)255;
    return p;
  };
  u16* lbuf = (u16*)alloc((size_t)L * 128 * 2);   // l_msg_feat, later l2l_msg
  u16* cmsg = (u16*)alloc((size_t)C * 128 * 2);
  u16* lagg = (u16*)alloc((size_t)L * 128 * 2);
  u16* cagg = (u16*)alloc((size_t)C * 128 * 2);
  float* la  = (float*)alloc((size_t)L * 4);
  float* lb  = (float*)alloc((size_t)L * 4);
  float* ca  = (float*)alloc((size_t)C * 4);
  float* cb  = (float*)alloc((size_t)C * 4);
  float* w1s = (float*)alloc((size_t)E * 4);
  float* w2e = (float*)alloc((size_t)E * 4);
  int* c_off_a = (int*)alloc((size_t)(C + 1) * 4);
  int* l_off_a = (int*)alloc((size_t)(L + 1) * 4);
  int* c_eid   = (int*)alloc((size_t)E * 4);
  int* l_eid   = (int*)alloc((size_t)E * 4);
  int* tmp     = (int*)alloc((size_t)(L + 1) * 4);
  const int PACK_TOTAL = 4 * 180224;
  u16* packW   = (u16*)alloc((size_t)PACK_TOTAL * 2);
  (void)ws_size; (void)n_in; (void)out_size;

  // slice 0 = copy of f32 inputs
  hipMemcpyAsync(out_l, l_emb0, (size_t)L * 128 * 4, hipMemcpyDeviceToDevice, stream);
  hipMemcpyAsync(out_c, c_emb0, (size_t)C * 128 * 4, hipMemcpyDeviceToDevice, stream);

  // weight repack (bf16 MFMA frag layout)
  k_packW<<<(PACK_TOTAL + 255) / 256, 256, 0, stream>>>(l2c_W, c2l_W, l2l_W, c_upd_W, l_upd_W,
                                                        packW, PACK_TOTAL);

  // clause CSR
  hipMemsetAsync(tmp, 0, (size_t)C * 4, stream);
  k_hist<<<1024, 256, 0, stream>>>(c_edge, tmp, E);
  k_exscan<<<1, 1024, 0, stream>>>(tmp, c_off_a, C);
  k_copyi<<<256, 256, 0, stream>>>(c_off_a, tmp, C);
  k_fill<<<1024, 256, 0, stream>>>(c_edge, tmp, c_eid, E);
  // literal CSR
  hipMemsetAsync(tmp, 0, (size_t)L * 4, stream);
  k_hist<<<1024, 256, 0, stream>>>(l_edge, tmp, E);
  k_exscan<<<1, 1024, 0, stream>>>(tmp, l_off_a, L);
  k_copyi<<<256, 256, 0, stream>>>(l_off_a, tmp, L);
  k_fill<<<1024, 256, 0, stream>>>(l_edge, tmp, l_eid, E);

  const size_t PI = 180224;
  for (int i = 0; i < 4; ++i) {
    const float* OL = out_l + (size_t)i * L * 128;
    const float* OC = out_c + (size_t)i * C * 128;
    float* OLn = out_l + (size_t)(i + 1) * L * 128;
    float* OCn = out_c + (size_t)(i + 1) * C * 128;

    const u16* pl2c0 = packW + i * PI;
    const u16* pl2c1 = packW + i * PI + 16384;
    const u16* pc2l0 = packW + i * PI + 32768;
    const u16* pc2l1 = packW + i * PI + 49152;
    const u16* pl2l0 = packW + i * PI + 65536;
    const u16* pl2l1 = packW + i * PI + 81920;
    const u16* pcupd = packW + i * PI + 98304;
    const u16* plupd = packW + i * PI + 131072;

    const float* b0l = l2c_b + (size_t)i * 2 * 128;
    const float* b0c = c2l_b + (size_t)i * 2 * 128;
    const float* b0x = l2l_b + (size_t)i * 2 * 128;

    // message MLPs (MFMA)
    k_mlp2_mfma<<<(L + 63) / 64, 256, 0, stream>>>(OL, pl2c0, b0l, pl2c1, b0l + 128, lbuf, L);
    k_mlp2_mfma<<<(C + 63) / 64, 256, 0, stream>>>(OC, pc2l0, b0c, pc2l1, b0c + 128, cmsg, C);

    // attention scalar factors
    k_dots<<<1024, 256, 0, stream>>>(OL, lbuf, l_att + (size_t)i * 256, c_att + (size_t)i * 256 + 128, lb, la, L);
    k_dots<<<512, 256, 0, stream>>>(OC, cmsg, c_att + (size_t)i * 256, l_att + (size_t)i * 256 + 128, ca, cb, C);

    // segmented softmax (both over clause segments; reference quirk)
    k_attw<<<(C * 16 + 255) / 256, 256, 0, stream>>>(c_off_a, c_eid, l_edge, ca, cb, la, lb, w1s, w2e, C);

    // aggregations
    k_aggr<<<C, 128, 0, stream>>>(c_off_a, c_eid, l_edge, w1s, 1, lbuf, cagg, C);
    k_aggr<<<L, 128, 0, stream>>>(l_off_a, l_eid, c_edge, w2e, 0, cmsg, lagg, L);

    // l2l MLP (after clause aggregation freed lbuf)
    k_mlp2_mfma<<<(L + 63) / 64, 256, 0, stream>>>(OL, pl2l0, b0x, pl2l1, b0x + 128, lbuf, L);

    // clause update -> next slice
    k_upd_mfma<256><<<(C + 63) / 64, 256, 0, stream>>>(
        OC, cagg, (const u16*)nullptr,
        pcupd, c_upd_b + (size_t)i * 128, OCn, C);

    // literal update -> next slice (xc read with XOR-1 row flip)
    k_upd_mfma<384><<<(L + 63) / 64, 256, 0, stream>>>(
        OL, lagg, lbuf,
        plupd, l_upd_b + (size_t)i * 128, OLn, L);
  }
}

// Round 5
// 1416.610 us; speedup vs baseline: 2.7701x; 1.3136x over previous
//
#include <hip/hip_runtime.h>

typedef unsigned short u16;
typedef unsigned int u32;
typedef __attribute__((ext_vector_type(8))) short s8v;   // 8 bf16 = 4 VGPR
typedef __attribute__((ext_vector_type(4))) float f4v;   // MFMA accum

// ---------- bf16 helpers ----------
__device__ __forceinline__ u16 f2bf(float f) {
  u32 u = __float_as_uint(f);
  u += 0x7FFFu + ((u >> 16) & 1u);
  return (u16)(u >> 16);
}
__device__ __forceinline__ float bf2f(u16 h) {
  return __uint_as_float(((u32)h) << 16);
}
__device__ __forceinline__ void unp2(u32 u, float& a, float& b) {
  a = __uint_as_float(u << 16);
  b = __uint_as_float(u & 0xFFFF0000u);
}
__device__ __forceinline__ u32 pk2(float a, float b) {
  return (u32)f2bf(a) | ((u32)f2bf(b) << 16);
}

// ---------- CSR build ----------
__global__ void k_hist(const int* __restrict__ seg, int* __restrict__ counts, int ne) {
  int i = blockIdx.x * blockDim.x + threadIdx.x, s = gridDim.x * blockDim.x;
  for (; i < ne; i += s) atomicAdd(&counts[seg[i]], 1);
}
__global__ void k_copyi(const int* __restrict__ a, int* __restrict__ b, int n) {
  int i = blockIdx.x * blockDim.x + threadIdx.x, s = gridDim.x * blockDim.x;
  for (; i < n; i += s) b[i] = a[i];
}
// literal CSR: store src clause row + edge->position map
__global__ void k_fill_l(const int* __restrict__ l_edge, const int* __restrict__ c_edge,
                         int* __restrict__ cursor, int* __restrict__ l_src,
                         int* __restrict__ l_posmap, int ne) {
  int i = blockIdx.x * blockDim.x + threadIdx.x, s = gridDim.x * blockDim.x;
  for (; i < ne; i += s) {
    int pos = atomicAdd(&cursor[l_edge[i]], 1);
    l_src[pos] = c_edge[i];
    l_posmap[i] = pos;
  }
}
// clause CSR: store src literal row + the literal-CSR position of this edge
__global__ void k_fill_c(const int* __restrict__ l_edge, const int* __restrict__ c_edge,
                         const int* __restrict__ l_posmap,
                         int* __restrict__ cursor, int* __restrict__ c_src,
                         int* __restrict__ c_lpos, int ne) {
  int i = blockIdx.x * blockDim.x + threadIdx.x, s = gridDim.x * blockDim.x;
  for (; i < ne; i += s) {
    int pos = atomicAdd(&cursor[c_edge[i]], 1);
    c_src[pos] = l_edge[i];
    c_lpos[pos] = l_posmap[i];
  }
}
__global__ void k_exscan(const int* __restrict__ counts, int* __restrict__ offs, int n) {
  __shared__ int part[1024];
  int tid = threadIdx.x;
  int per = (n + 1023) >> 10;
  int start = tid * per;
  int s = 0;
  for (int k = 0; k < per; ++k) { int idx = start + k; if (idx < n) s += counts[idx]; }
  part[tid] = s; __syncthreads();
  for (int d = 1; d < 1024; d <<= 1) {
    int v = (tid >= d) ? part[tid - d] : 0;
    __syncthreads();
    part[tid] += v;
    __syncthreads();
  }
  int run = (tid == 0) ? 0 : part[tid - 1];
  for (int k = 0; k < per; ++k) { int idx = start + k; if (idx < n) { offs[idx] = run; run += counts[idx]; } }
  if (tid == 0) offs[n] = part[1023];
}

// ---------- weight repack: f32 [K][128] -> bf16 MFMA B-frag layout ----------
__global__ void k_packW(const float* __restrict__ l2c_W, const float* __restrict__ c2l_W,
                        const float* __restrict__ l2l_W, const float* __restrict__ c_upd_W,
                        const float* __restrict__ l_upd_W, u16* __restrict__ dst, int total) {
  int o = blockIdx.x * blockDim.x + threadIdx.x;
  if (o >= total) return;
  int it = o / 180224;
  int r = o - it * 180224;
  const float* src;
  int o2;
  if (r < 98304) {
    int m = r >> 14;           // 0..5
    o2 = r & 16383;
    if (m < 2)      src = l2c_W + ((size_t)it * 2 + m) * 16384;
    else if (m < 4) src = c2l_W + ((size_t)it * 2 + (m - 2)) * 16384;
    else            src = l2l_W + ((size_t)it * 2 + (m - 4)) * 16384;
  } else if (r < 131072) {
    o2 = r - 98304;  src = c_upd_W + (size_t)it * 32768;
  } else {
    o2 = r - 131072; src = l_upd_W + (size_t)it * 49152;
  }
  int j = o2 & 7, lane = (o2 >> 3) & 63, f = o2 >> 9;
  int nt = f & 7, kc = f >> 3;
  int k = kc * 32 + ((lane >> 4) << 3) + j;
  int nn = nt * 16 + (lane & 15);
  dst[o] = f2bf(src[(size_t)k * 128 + nn]);
}

// ---------- fused 2-layer MLP via MFMA + fused attention dots ----------
// x f32, packed bf16 weights, y bf16. dx[r]=x[r].attx  dy[r]=y[r].atty (skipped if null)
__global__ __launch_bounds__(256) void k_mlp2_mfma(
    const float* __restrict__ x,
    const u16* __restrict__ pW0, const float* __restrict__ b0,
    const u16* __restrict__ pW1, const float* __restrict__ b1,
    u16* __restrict__ y,
    const float* __restrict__ attx, const float* __restrict__ atty,
    float* __restrict__ dx, float* __restrict__ dy, int n)
{
  __shared__ u16 xs[64][136];
  __shared__ u16 hs[64][136];
  const int tid = threadIdx.x;
  const int lane = tid & 63;
  const int w = tid >> 6;
  const int r0 = blockIdx.x * 64;
  for (int t = tid; t < 64 * 32; t += 256) {
    int row = t >> 5, ch = t & 31; int gr = r0 + row;
    float4 v = make_float4(0.f, 0.f, 0.f, 0.f);
    if (gr < n) v = *(const float4*)(x + (size_t)gr * 128 + ch * 4);
    u16* p = &xs[row][ch * 4];
    p[0] = f2bf(v.x); p[1] = f2bf(v.y); p[2] = f2bf(v.z); p[3] = f2bf(v.w);
  }
  __syncthreads();

  // fused x-dot: dx[row] = x[row] . attx   (wave w owns rows w*16..w*16+15)
  if (attx) {
    float2 ax = *(const float2*)(attx + lane * 2);
    for (int r = 0; r < 16; ++r) {
      int row = w * 16 + r; int gr = r0 + row;
      u32 v = *(const u32*)&xs[row][lane * 2];
      float f0, f1; unp2(v, f0, f1);
      float p = f0 * ax.x + f1 * ax.y;
#pragma unroll
      for (int d = 32; d >= 1; d >>= 1) p += __shfl_xor(p, d);
      if (lane == 0 && gr < n) dx[gr] = p;
    }
  }

  const int arow = w * 16 + (lane & 15);
  const int kgrp = (lane >> 4) * 8;
  const int dcol = lane & 15;
  const int drow0 = w * 16 + (lane >> 4) * 4;
  f4v acc[8];
  // layer 0
#pragma unroll
  for (int nt = 0; nt < 8; ++nt) {
    float bv = b0[nt * 16 + dcol];
    acc[nt] = (f4v){bv, bv, bv, bv};
  }
#pragma unroll
  for (int kc = 0; kc < 4; ++kc) {
    s8v a = *(const s8v*)&xs[arow][kc * 32 + kgrp];
#pragma unroll
    for (int nt = 0; nt < 8; ++nt) {
      s8v b = *(const s8v*)(pW0 + ((size_t)(kc * 8 + nt) * 64 + lane) * 8);
      acc[nt] = __builtin_amdgcn_mfma_f32_16x16x32_bf16(a, b, acc[nt], 0, 0, 0);
    }
  }
#pragma unroll
  for (int nt = 0; nt < 8; ++nt)
#pragma unroll
    for (int r = 0; r < 4; ++r)
      hs[drow0 + r][nt * 16 + dcol] = f2bf(fmaxf(acc[nt][r], 0.f));
  __syncthreads();
  // layer 1
#pragma unroll
  for (int nt = 0; nt < 8; ++nt) {
    float bv = b1[nt * 16 + dcol];
    acc[nt] = (f4v){bv, bv, bv, bv};
  }
#pragma unroll
  for (int kc = 0; kc < 4; ++kc) {
    s8v a = *(const s8v*)&hs[arow][kc * 32 + kgrp];
#pragma unroll
    for (int nt = 0; nt < 8; ++nt) {
      s8v b = *(const s8v*)(pW1 + ((size_t)(kc * 8 + nt) * 64 + lane) * 8);
      acc[nt] = __builtin_amdgcn_mfma_f32_16x16x32_bf16(a, b, acc[nt], 0, 0, 0);
    }
  }
#pragma unroll
  for (int nt = 0; nt < 8; ++nt)
#pragma unroll
    for (int r = 0; r < 4; ++r) {
      int gr = r0 + drow0 + r;
      if (gr < n) y[(size_t)gr * 128 + nt * 16 + dcol] = f2bf(acc[nt][r]);
    }

  // fused y-dot: dy[row] = y[row] . atty  (from f32 accumulators)
  if (atty) {
    float pr[4] = {0.f, 0.f, 0.f, 0.f};
#pragma unroll
    for (int nt = 0; nt < 8; ++nt) {
      float av = atty[nt * 16 + dcol];
#pragma unroll
      for (int r = 0; r < 4; ++r) pr[r] = fmaf(acc[nt][r], av, pr[r]);
    }
#pragma unroll
    for (int d = 8; d >= 1; d >>= 1)
#pragma unroll
      for (int r = 0; r < 4; ++r) pr[r] += __shfl_xor(pr[r], d);
    if ((lane & 15) == 0) {
#pragma unroll
      for (int r = 0; r < 4; ++r) {
        int gr = r0 + drow0 + r;
        if (gr < n) dy[gr] = pr[r];
      }
    }
  }
}

// ---------- update GEMM via MFMA: out = concat(xa, xb [, xc[r^1]]) @ W + bias ----------
template <int KTOT>
__global__ __launch_bounds__(256) void k_upd_mfma(
    const float* __restrict__ xa, const u16* __restrict__ xb, const u16* __restrict__ xc,
    const u16* __restrict__ pW, const float* __restrict__ bias,
    float* __restrict__ ob, int n)
{
  constexpr int KP = KTOT + 8;
  __shared__ u16 xs[64][KP];
  const int tid = threadIdx.x;
  const int lane = tid & 63;
  const int w = tid >> 6;
  const int r0 = blockIdx.x * 64;
  for (int t = tid; t < 64 * 32; t += 256) {
    int row = t >> 5, ch = t & 31; int gr = r0 + row;
    float4 v = make_float4(0.f, 0.f, 0.f, 0.f);
    if (gr < n) v = *(const float4*)(xa + (size_t)gr * 128 + ch * 4);
    u16* p = &xs[row][ch * 4];
    p[0] = f2bf(v.x); p[1] = f2bf(v.y); p[2] = f2bf(v.z); p[3] = f2bf(v.w);
  }
  for (int t = tid; t < 64 * 16; t += 256) {
    int row = t >> 4, ch = t & 15; int gr = r0 + row;
    uint4 v = make_uint4(0, 0, 0, 0);
    if (gr < n) v = *(const uint4*)(xb + (size_t)gr * 128 + ch * 8);
    *(uint4*)&xs[row][128 + ch * 8] = v;
  }
  if (KTOT > 256) {
    for (int t = tid; t < 64 * 16; t += 256) {
      int row = t >> 4, ch = t & 15; int gr = r0 + row;
      uint4 v = make_uint4(0, 0, 0, 0);
      if (gr < n) v = *(const uint4*)(xc + (size_t)(gr ^ 1) * 128 + ch * 8);
      *(uint4*)&xs[row][256 + ch * 8] = v;
    }
  }
  __syncthreads();
  const int arow = w * 16 + (lane & 15);
  const int kgrp = (lane >> 4) * 8;
  const int dcol = lane & 15;
  const int drow0 = w * 16 + (lane >> 4) * 4;
  f4v acc[8];
#pragma unroll
  for (int nt = 0; nt < 8; ++nt) {
    float bv = bias[nt * 16 + dcol];
    acc[nt] = (f4v){bv, bv, bv, bv};
  }
#pragma unroll
  for (int kc = 0; kc < KTOT / 32; ++kc) {
    s8v a = *(const s8v*)&xs[arow][kc * 32 + kgrp];
#pragma unroll
    for (int nt = 0; nt < 8; ++nt) {
      s8v b = *(const s8v*)(pW + ((size_t)(kc * 8 + nt) * 64 + lane) * 8);
      acc[nt] = __builtin_amdgcn_mfma_f32_16x16x32_bf16(a, b, acc[nt], 0, 0, 0);
    }
  }
#pragma unroll
  for (int nt = 0; nt < 8; ++nt)
#pragma unroll
    for (int r = 0; r < 4; ++r) {
      int gr = r0 + drow0 + r;
      if (gr < n) ob[(size_t)gr * 128 + nt * 16 + dcol] = acc[nt][r];
    }
}

// ---------- attention softmax, one wave per clause, single pass (deg<=64) ----------
__global__ __launch_bounds__(256) void k_attw(
    const int* __restrict__ c_off, const int* __restrict__ c_src, const int* __restrict__ c_lpos,
    const float* __restrict__ ca, const float* __restrict__ cb,
    const float* __restrict__ la, const float* __restrict__ lb,
    float* __restrict__ w1s, float* __restrict__ w2p, int C)
{
  const int lane = threadIdx.x & 63;
  const int gid = blockIdx.x * 4 + (threadIdx.x >> 6);
  if (gid >= C) return;
  const int off = c_off[gid];
  const int deg = c_off[gid + 1] - off;
  if (deg == 0) return;
  const float cav = ca[gid], cbv = cb[gid];
  if (deg <= 64) {
    int lp = 0;
    float s1 = -3.0e38f, s2 = -3.0e38f;
    bool on = lane < deg;
    if (on) {
      int l_ = c_src[off + lane];
      lp = c_lpos[off + lane];
      float lav = la[l_], lbv = lb[l_];
      s1 = cav + lav; s1 = s1 > 0.f ? s1 : 0.2f * s1;
      s2 = lbv + cbv; s2 = s2 > 0.f ? s2 : 0.2f * s2;
    }
    float m1 = s1, m2 = s2;
#pragma unroll
    for (int d = 32; d >= 1; d >>= 1) {
      m1 = fmaxf(m1, __shfl_xor(m1, d));
      m2 = fmaxf(m2, __shfl_xor(m2, d));
    }
    float e1 = on ? __expf(s1 - m1) : 0.f;
    float e2 = on ? __expf(s2 - m2) : 0.f;
    float z1 = e1, z2 = e2;
#pragma unroll
    for (int d = 32; d >= 1; d >>= 1) {
      z1 += __shfl_xor(z1, d);
      z2 += __shfl_xor(z2, d);
    }
    if (on) {
      w1s[off + lane] = e1 / (z1 + 1e-16f);
      w2p[lp] = e2 / (z2 + 1e-16f);
    }
  } else {
    // chunked 3-pass fallback (rare)
    float m1 = -3.0e38f, m2 = -3.0e38f;
    for (int base = 0; base < deg; base += 64) {
      int idx = base + lane;
      if (idx < deg) {
        int l_ = c_src[off + idx];
        float s1 = cav + la[l_]; s1 = s1 > 0.f ? s1 : 0.2f * s1;
        float s2 = lb[l_] + cbv; s2 = s2 > 0.f ? s2 : 0.2f * s2;
        m1 = fmaxf(m1, s1); m2 = fmaxf(m2, s2);
      }
    }
#pragma unroll
    for (int d = 32; d >= 1; d >>= 1) {
      m1 = fmaxf(m1, __shfl_xor(m1, d));
      m2 = fmaxf(m2, __shfl_xor(m2, d));
    }
    float z1 = 0.f, z2 = 0.f;
    for (int base = 0; base < deg; base += 64) {
      int idx = base + lane;
      if (idx < deg) {
        int l_ = c_src[off + idx];
        float s1 = cav + la[l_]; s1 = s1 > 0.f ? s1 : 0.2f * s1;
        float s2 = lb[l_] + cbv; s2 = s2 > 0.f ? s2 : 0.2f * s2;
        float e1 = __expf(s1 - m1), e2 = __expf(s2 - m2);
        w1s[off + idx] = e1; w2p[c_lpos[off + idx]] = e2;
        z1 += e1; z2 += e2;
      }
    }
#pragma unroll
    for (int d = 32; d >= 1; d >>= 1) { z1 += __shfl_xor(z1, d); z2 += __shfl_xor(z2, d); }
    float i1 = 1.f / (z1 + 1e-16f), i2 = 1.f / (z2 + 1e-16f);
    for (int base = 0; base < deg; base += 64) {
      int idx = base + lane;
      if (idx < deg) {
        w1s[off + idx] *= i1;
        w2p[c_lpos[off + idx]] *= i2;
      }
    }
  }
}

// ---------- positional weighted aggregation: out[seg] = sum_j w[j]*feat[src[j]] ----------
// one wave per segment; 64 lanes cover 128 bf16 dims as u32 pairs
__global__ __launch_bounds__(256) void k_aggr(
    const int* __restrict__ offs, const float* __restrict__ w, const int* __restrict__ src,
    const u32* __restrict__ feat32, u32* __restrict__ out32, int nseg)
{
  const int lane = threadIdx.x & 63;
  const int seg = blockIdx.x * 4 + (threadIdx.x >> 6);
  if (seg >= nseg) return;
  const int off = offs[seg];
  const int deg = offs[seg + 1] - off;
  float a0 = 0.f, a1 = 0.f;
  for (int base = 0; base < deg; base += 64) {
    int m = deg - base; if (m > 64) m = 64;
    float wv = 0.f; int sv = 0;
    if (lane < m) { wv = w[off + base + lane]; sv = src[off + base + lane]; }
    for (int j = 0; j < m; ++j) {
      int sj = __shfl(sv, j);
      float wj = __shfl(wv, j);
      u32 d = feat32[(size_t)sj * 64 + lane];
      float f0, f1; unp2(d, f0, f1);
      a0 = fmaf(wj, f0, a0);
      a1 = fmaf(wj, f1, a1);
    }
  }
  out32[(size_t)seg * 64 + lane] = pk2(a0, a1);
}

// ---------- host launch ----------
extern "C" void kernel_launch(void* const* d_in, const int* in_sizes, int n_in,
                              void* d_out, int out_size, void* d_ws, size_t ws_size,
                              hipStream_t stream)
{
  const float* l_emb0  = (const float*)d_in[0];
  const float* c_emb0  = (const float*)d_in[1];
  const float* l2c_W   = (const float*)d_in[2];
  const float* l2c_b   = (const float*)d_in[3];
  const float* c2l_W   = (const float*)d_in[4];
  const float* c2l_b   = (const float*)d_in[5];
  const float* l2l_W   = (const float*)d_in[6];
  const float* l2l_b   = (const float*)d_in[7];
  const float* c_att   = (const float*)d_in[8];
  const float* l_att   = (const float*)d_in[9];
  const float* c_upd_W = (const float*)d_in[10];
  const float* c_upd_b = (const float*)d_in[11];
  const float* l_upd_W = (const float*)d_in[12];
  const float* l_upd_b = (const float*)d_in[13];
  const int* l_edge    = (const int*)d_in[14];
  const int* c_edge    = (const int*)d_in[15];

  const int L = in_sizes[0] / 128;
  const int C = in_sizes[1] / 128;
  const int E = in_sizes[14];

  float* out_l = (float*)d_out;                    // [5][L][128] f32
  float* out_c = out_l + (size_t)5 * L * 128;      // [5][C][128] f32

  char* wsb = (char*)d_ws;
  size_t off = 0;
  auto alloc = [&](size_t bytes) -> char* {
    char* p = wsb + off;
    off = (off + bytes + 255) & ~(size_t)255;
    return p;
  };
  u16* lbuf = (u16*)alloc((size_t)L * 128 * 2);   // l_msg_feat, later l2l_msg
  u16* cmsg = (u16*)alloc((size_t)C * 128 * 2);
  u16* lagg = (u16*)alloc((size_t)L * 128 * 2);
  u16* cagg = (u16*)alloc((size_t)C * 128 * 2);
  float* la  = (float*)alloc((size_t)L * 4);
  float* lb  = (float*)alloc((size_t)L * 4);
  float* ca  = (float*)alloc((size_t)C * 4);
  float* cb  = (float*)alloc((size_t)C * 4);
  float* w1s = (float*)alloc((size_t)E * 4);
  float* w2p = (float*)alloc((size_t)E * 4);
  int* c_off_a = (int*)alloc((size_t)(C + 1) * 4);
  int* l_off_a = (int*)alloc((size_t)(L + 1) * 4);
  int* l_src   = (int*)alloc((size_t)E * 4);
  int* l_posmap= (int*)alloc((size_t)E * 4);
  int* c_src   = (int*)alloc((size_t)E * 4);
  int* c_lpos  = (int*)alloc((size_t)E * 4);
  int* tmp     = (int*)alloc((size_t)(L + 1) * 4);
  const int PACK_TOTAL = 4 * 180224;
  u16* packW   = (u16*)alloc((size_t)PACK_TOTAL * 2);
  (void)ws_size; (void)n_in; (void)out_size;

  // slice 0 = copy of f32 inputs
  hipMemcpyAsync(out_l, l_emb0, (size_t)L * 128 * 4, hipMemcpyDeviceToDevice, stream);
  hipMemcpyAsync(out_c, c_emb0, (size_t)C * 128 * 4, hipMemcpyDeviceToDevice, stream);

  // weight repack (bf16 MFMA frag layout)
  k_packW<<<(PACK_TOTAL + 255) / 256, 256, 0, stream>>>(l2c_W, c2l_W, l2l_W, c_upd_W, l_upd_W,
                                                        packW, PACK_TOTAL);

  // literal CSR (first: produces l_posmap needed by clause CSR)
  hipMemsetAsync(tmp, 0, (size_t)L * 4, stream);
  k_hist<<<1024, 256, 0, stream>>>(l_edge, tmp, E);
  k_exscan<<<1, 1024, 0, stream>>>(tmp, l_off_a, L);
  k_copyi<<<256, 256, 0, stream>>>(l_off_a, tmp, L);
  k_fill_l<<<1024, 256, 0, stream>>>(l_edge, c_edge, tmp, l_src, l_posmap, E);
  // clause CSR
  hipMemsetAsync(tmp, 0, (size_t)C * 4, stream);
  k_hist<<<1024, 256, 0, stream>>>(c_edge, tmp, E);
  k_exscan<<<1, 1024, 0, stream>>>(tmp, c_off_a, C);
  k_copyi<<<256, 256, 0, stream>>>(c_off_a, tmp, C);
  k_fill_c<<<1024, 256, 0, stream>>>(l_edge, c_edge, l_posmap, tmp, c_src, c_lpos, E);

  const size_t PI = 180224;
  for (int i = 0; i < 4; ++i) {
    const float* OL = out_l + (size_t)i * L * 128;
    const float* OC = out_c + (size_t)i * C * 128;
    float* OLn = out_l + (size_t)(i + 1) * L * 128;
    float* OCn = out_c + (size_t)(i + 1) * C * 128;

    const u16* pl2c0 = packW + i * PI;
    const u16* pl2c1 = packW + i * PI + 16384;
    const u16* pc2l0 = packW + i * PI + 32768;
    const u16* pc2l1 = packW + i * PI + 49152;
    const u16* pl2l0 = packW + i * PI + 65536;
    const u16* pl2l1 = packW + i * PI + 81920;
    const u16* pcupd = packW + i * PI + 98304;
    const u16* plupd = packW + i * PI + 131072;

    const float* b0l = l2c_b + (size_t)i * 2 * 128;
    const float* b0c = c2l_b + (size_t)i * 2 * 128;
    const float* b0x = l2l_b + (size_t)i * 2 * 128;

    // message MLPs with fused attention dots:
    // lb = OL.l_att[:128], la = lbuf.c_att[128:]
    k_mlp2_mfma<<<(L + 63) / 64, 256, 0, stream>>>(
        OL, pl2c0, b0l, pl2c1, b0l + 128, lbuf,
        l_att + (size_t)i * 256, c_att + (size_t)i * 256 + 128, lb, la, L);
    // ca = OC.c_att[:128], cb = cmsg.l_att[128:]
    k_mlp2_mfma<<<(C + 63) / 64, 256, 0, stream>>>(
        OC, pc2l0, b0c, pc2l1, b0c + 128, cmsg,
        c_att + (size_t)i * 256, l_att + (size_t)i * 256 + 128, ca, cb, C);

    // segmented softmax (both over clause segments; reference quirk)
    k_attw<<<(C + 3) / 4, 256, 0, stream>>>(c_off_a, c_src, c_lpos, ca, cb, la, lb, w1s, w2p, C);

    // aggregations (positional, coalesced meta)
    k_aggr<<<(C + 3) / 4, 256, 0, stream>>>(c_off_a, w1s, c_src, (const u32*)lbuf, (u32*)cagg, C);
    k_aggr<<<(L + 3) / 4, 256, 0, stream>>>(l_off_a, w2p, l_src, (const u32*)cmsg, (u32*)lagg, L);

    // l2l MLP (after clause aggregation freed lbuf), no dots
    k_mlp2_mfma<<<(L + 63) / 64, 256, 0, stream>>>(
        OL, pl2l0, b0x, pl2l1, b0x + 128, lbuf,
        (const float*)nullptr, (const float*)nullptr, (float*)nullptr, (float*)nullptr, L);

    // clause update -> next slice
    k_upd_mfma<256><<<(C + 63) / 64, 256, 0, stream>>>(
        OC, cagg, (const u16*)nullptr,
        pcupd, c_upd_b + (size_t)i * 128, OCn, C);

    // literal update -> next slice (xc read with XOR-1 row flip)
    k_upd_mfma<384><<<(L + 63) / 64, 256, 0, stream>>>(
        OL, lagg, lbuf,
        plupd, l_upd_b + (size_t)i * 128, OLn, L);
  }
}